// Round 1
// 99.956 us; speedup vs baseline: 1.0602x; 1.0602x over previous
//
#include <hip/hip_runtime.h>
#include <math.h>

// Adder2D: out[n,co,h,w] = -sum_{ci,kh,kw} |x[n,ci,h+kh-1,w+kw-1] - w[co,ci,kh,kw]|
// x: [16,64,32,32] f32, w: [64,64,3,3] f32, out: [16,64,32,32] f32, pad=1 stride=1.
//
// R4: occupancy + LDS-read cleanup. R3 was latency-bound: grid 512 x 256 thr
// = 2 waves/SIMD (Occ 18%), true VALU busy ~32% (derived 64% is the gfx94x
// 2x-inflated formula). Decomposition pinned threads at 131k (25% of slots).
// Now: split-K over ci -- 512-thread blocks, two 256-thread ci-groups each
// compute half the planes of every staged round; partials combined via an
// 8KB LDS buffer. Same grid (512 blocks, 2/CU) -> 16 waves/CU, 4 waves/SIMD.
// Also: 36-wide LDS rows with zero halo cols (col 0 / col 33) so each kh
// needs just two aligned float2 LDS reads (ds_read2_b64): removes the 6
// scalar odd-bank reads (the 2.09M bank-conflict source) + 6 cndmask per ci.

#define N_   16
#define CI_  64
#define CO_  64
#define HW_  32
#define CG   4      // co per thread
#define COB  8      // co per block
#define RG   8      // pixel rows per block
#define CIC  16     // ci planes staged per round
#define CPG  8      // ci planes computed per group per round
#define ROWS (RG + 2)
#define LW   36     // LDS row stride: col0 = left halo, 1..32 = data, 33 = right halo, 34-35 pad

__global__ __launch_bounds__(512, 4) void adder2d_kernel(
    const float* __restrict__ x, const float* __restrict__ w,
    float* __restrict__ out)
{
    __shared__ __align__(16) float xs[CIC][ROWS][LW];    // 23040 B
    __shared__ __align__(16) float ws[CI_][9][COB];      // 18432 B
    __shared__ __align__(16) float red[256][8];          //  8192 B  (49664 total)

    const int tid   = threadIdx.x;
    const int u     = tid & 15;          // col-pair: pixels at cols 2u, 2u+1
    const int rl    = (tid >> 4) & 7;    // pixel row within block
    const int cosub = (tid >> 7) & 1;    // co half
    const int cig   = tid >> 8;          // ci group: 0 or 1
    const int r0    = blockIdx.x * RG;
    const int co0   = blockIdx.y * COB;
    const int n     = blockIdx.z;

    // ---- stage w once: w[co0+cl][ci][t] -> ws[ci][t][cl]  (9 iters) ----
    for (int i = tid; i < COB * CI_ * 9; i += 512) {
        int cl  = i / (CI_ * 9);
        int rem = i - cl * (CI_ * 9);    // = ci*9 + t
        ws[rem / 9][rem % 9][cl] = w[(co0 + cl) * (CI_ * 9) + rem];
    }
    // ---- zero all of xs once: halo cols (0,33) and OOB row slots stay
    //      zero forever; staging rewrites only in-bounds data cols ----
    for (int i = tid; i < CIC * ROWS * (LW / 4); i += 512)
        ((float4*)xs)[i] = float4{0.f, 0.f, 0.f, 0.f};

    float acc0[CG], acc1[CG];
#pragma unroll
    for (int j = 0; j < CG; ++j) { acc0[j] = 0.f; acc1[j] = 0.f; }

    const float* xn = x + (size_t)n * CI_ * HW_ * HW_;

    // staging map: 512 threads = 16 planes x 32 threads.
    // thread loads rows {sq, sq+4, sq+8} (guarded), float4 index sf.
    const int sp = tid >> 5;             // plane 0..15
    const int sf = tid & 7;              // float4 index within a 32-col row
    const int sq = (tid >> 3) & 3;       // row group 0..3

    for (int round = 0; round < CI_ / CIC; ++round) {
        const int cc0 = round * CIC;
        __syncthreads();   // protect LDS from previous round's readers
#pragma unroll
        for (int it = 0; it < 3; ++it) {
            int rr = sq + 4 * it;
            if (rr < ROWS) {
                int gr = r0 - 1 + rr;
                if ((unsigned)gr < HW_) {
                    float4 v = ((const float4*)(xn + (size_t)(cc0 + sp) * HW_ * HW_
                                                + gr * HW_))[sf];
                    float* dst = &xs[sp][rr][1 + 4 * sf];   // data cols start at 1
                    dst[0] = v.x; dst[1] = v.y; dst[2] = v.z; dst[3] = v.w;
                }
            }
        }
        __syncthreads();

        const int pbase = cig * CPG;
#pragma unroll 4
        for (int cil = 0; cil < CPG; ++cil) {
            const int pl = pbase + cil;
            const int ci = cc0 + pl;

            // 9 b128 broadcasts: wv[t][j] = w[co0+4*cosub+j][ci][t]
            float4 wv[9];
#pragma unroll
            for (int t = 0; t < 9; ++t)
                wv[t] = *(const float4*)&ws[ci][t][cosub * CG];

            // x patch for 2 pixels: rows rl..rl+2, storage cols 2u..2u+3
            // (= real cols 2u-1..2u+2, halos pre-zeroed). Aligned 2x float2.
            float4 xv[3];
#pragma unroll
            for (int kh = 0; kh < 3; ++kh) {
                const float* row = &xs[pl][rl + kh][2 * u];
                float2 lo = *(const float2*)&row[0];
                float2 hi = *(const float2*)&row[2];
                xv[kh] = float4{lo.x, lo.y, hi.x, hi.y};
            }

            // 144 VALU: 2 pix x 4 co x 9 taps, sub + add-with-|.|-modifier
#pragma unroll
            for (int kh = 0; kh < 3; ++kh)
#pragma unroll
                for (int kw = 0; kw < 3; ++kw) {
                    const int t = kh * 3 + kw;
                    float xa = (kw == 0) ? xv[kh].x : ((kw == 1) ? xv[kh].y : xv[kh].z);
                    float xb = (kw == 0) ? xv[kh].y : ((kw == 1) ? xv[kh].z : xv[kh].w);
                    const float* wj = (const float*)&wv[t];
#pragma unroll
                    for (int j = 0; j < CG; ++j) {
                        acc0[j] += fabsf(xa - wj[j]);
                        acc1[j] += fabsf(xb - wj[j]);
                    }
                }
        }
    }

    // ---- combine the two ci-halves, then store (group 0 only) ----
    if (cig == 1) {
        int t = tid - 256;
        *(float4*)&red[t][0] = float4{acc0[0], acc0[1], acc0[2], acc0[3]};
        *(float4*)&red[t][4] = float4{acc1[0], acc1[1], acc1[2], acc1[3]};
    }
    __syncthreads();
    if (cig == 0) {
        float4 ra = *(const float4*)&red[tid][0];
        float4 rb = *(const float4*)&red[tid][4];
        acc0[0] += ra.x; acc0[1] += ra.y; acc0[2] += ra.z; acc0[3] += ra.w;
        acc1[0] += rb.x; acc1[1] += rb.y; acc1[2] += rb.z; acc1[3] += rb.w;

        float* op = out + (((size_t)n * CO_ + co0 + cosub * CG) * HW_ + (r0 + rl)) * HW_ + 2 * u;
#pragma unroll
        for (int j = 0; j < CG; ++j)
            *(float2*)&op[(size_t)j * HW_ * HW_] = float2{-acc0[j], -acc1[j]};
    }
}

extern "C" void kernel_launch(void* const* d_in, const int* in_sizes, int n_in,
                              void* d_out, int out_size, void* d_ws, size_t ws_size,
                              hipStream_t stream) {
    const float* x  = (const float*)d_in[0];
    const float* wp = (const float*)d_in[1];
    float* out      = (float*)d_out;
    dim3 grid(HW_ / RG, CO_ / COB, N_);   // (4, 8, 16) = 512 blocks
    adder2d_kernel<<<grid, 512, 0, stream>>>(x, wp, out);
}